// Round 3
// baseline (720.516 us; speedup 1.0000x reference)
//
#include <hip/hip_runtime.h>

#define DH 15

// ---- stable tanh + derivative factors -------------------------------------
// t = tanh(u), s = sech^2(u), f2 = t'', f3 = t''', f4 = t''''
__device__ __forceinline__ void tanh_fs(float u0, float& t, float& s,
                                        float& f2, float& f3, float& f4) {
    float e = __builtin_amdgcn_exp2f(u0 * 2.885390081777927f); // exp(2*u0)
    float r = __builtin_amdgcn_rcpf(1.0f + e);
    t = 1.0f - 2.0f * r;
    s = 4.0f * r * (1.0f - r);           // no inf*0, no cancellation
    f2 = -2.0f * t * s;
    f3 = s * (4.0f * t * t - 2.0f * s);
    f4 = 8.0f * t * s * (2.0f * s - t * t);
}

// degree-4 jet composition h = tanh(u) (Faà di Bruno)
__device__ __forceinline__ void tanh_jet(float u0, float u1, float u2,
                                         float u3, float u4, float h[5]) {
    float t, s, f2, f3, f4;
    tanh_fs(u0, t, s, f2, f3, f4);
    float u1s = u1 * u1;
    h[0] = t;
    h[1] = s * u1;
    h[2] = f2 * u1s + s * u2;
    h[3] = f3 * u1s * u1 + 3.0f * f2 * u1 * u2 + s * u3;
    h[4] = f4 * u1s * u1s + 6.0f * f3 * u1s * u2
         + f2 * (3.0f * u2 * u2 + 4.0f * u1 * u3) + s * u4;
}

// dense 15->15 + tanh on jets. Weights/biases read directly from global with
// compile-time-uniform addresses -> compiler emits s_load, values live in
// SGPRs (v_fma with one SGPR source). No weight VGPRs, no LDS.
// sched_barrier(0) per row bounds both VGPR temp ranges and s_load hoisting.
__device__ __forceinline__ void dense_tanh(float h[DH][5],
                                           const float* __restrict__ W,
                                           const float* __restrict__ B) {
    float u[DH][5];
    {   // k = 0 peeled: fold init into FMAs (no zero-movs)
        float h0 = h[0][0], h1 = h[0][1], h2 = h[0][2], h3 = h[0][3], h4 = h[0][4];
#pragma unroll
        for (int j = 0; j < DH; ++j) {
            float w = W[j];
            u[j][0] = fmaf(h0, w, B[j]);
            u[j][1] = h1 * w;
            u[j][2] = h2 * w;
            u[j][3] = h3 * w;
            u[j][4] = h4 * w;
        }
        __builtin_amdgcn_sched_barrier(0);
    }
#pragma unroll
    for (int k = 1; k < DH; ++k) {
        float h0 = h[k][0], h1 = h[k][1], h2 = h[k][2], h3 = h[k][3], h4 = h[k][4];
#pragma unroll
        for (int j = 0; j < DH; ++j) {
            float w = W[k * DH + j];
            u[j][0] = fmaf(h0, w, u[j][0]);
            u[j][1] = fmaf(h1, w, u[j][1]);
            u[j][2] = fmaf(h2, w, u[j][2]);
            u[j][3] = fmaf(h3, w, u[j][3]);
            u[j][4] = fmaf(h4, w, u[j][4]);
        }
        __builtin_amdgcn_sched_barrier(0);
    }
#pragma unroll
    for (int j = 0; j < DH; ++j) {
        float hj[5];
        tanh_jet(u[j][0], u[j][1], u[j][2], u[j][3], u[j][4], hj);
        h[j][0] = hj[0]; h[j][1] = hj[1]; h[j][2] = hj[2];
        h[j][3] = hj[3]; h[j][4] = hj[4];
        __builtin_amdgcn_sched_barrier(0);
    }
}

// full degree-4 jet through the MLP for one scalar x (SGPR weights)
__device__ __forceinline__ void jet_eval(float xv,
                                         const float* __restrict__ W1,
                                         const float* __restrict__ b1,
                                         const float* __restrict__ W2,
                                         const float* __restrict__ b2,
                                         const float* __restrict__ W3,
                                         const float* __restrict__ b3,
                                         const float* __restrict__ W4,
                                         const float* __restrict__ b4,
                                         float o[5]) {
    float h[DH][5];
#pragma unroll
    for (int j = 0; j < DH; ++j) {
        float w = W1[j];
        float t, s, f2, f3, f4;
        tanh_fs(fmaf(xv, w, b1[j]), t, s, f2, f3, f4);
        float w2 = w * w;
        h[j][0] = t;
        h[j][1] = s * w;
        h[j][2] = f2 * w2;
        h[j][3] = f3 * w2 * w;
        h[j][4] = f4 * w2 * w2;
        __builtin_amdgcn_sched_barrier(0);
    }
    dense_tanh(h, W2, b2);
    dense_tanh(h, W3, b3);
    float o0 = b4[0], o1 = 0.f, o2 = 0.f, o3 = 0.f, o4 = 0.f;
#pragma unroll
    for (int k = 0; k < DH; ++k) {
        float w = W4[k];
        o0 = fmaf(h[k][0], w, o0);
        o1 = fmaf(h[k][1], w, o1);
        o2 = fmaf(h[k][2], w, o2);
        o3 = fmaf(h[k][3], w, o3);
        o4 = fmaf(h[k][4], w, o4);
    }
    o[0] = o0; o[1] = o1; o[2] = o2; o[3] = o3; o[4] = o4;
}

// ---- main kernel: per-point degree-4 jet, reduce (w''''+1)^2 ----------------
__global__ void __launch_bounds__(256, 3)
pinn_main(const float* __restrict__ x,
          const float* __restrict__ W1, const float* __restrict__ b1,
          const float* __restrict__ W2, const float* __restrict__ b2,
          const float* __restrict__ W3, const float* __restrict__ b3,
          const float* __restrict__ W4, const float* __restrict__ b4,
          double* __restrict__ partials, int N) {
    int tid = threadIdx.x;
    float acc = 0.0f;
    int idx0 = blockIdx.x * blockDim.x + tid;
    int gsz = gridDim.x * blockDim.x;
    for (int i = idx0; i < N; i += gsz) {
        float xv = x[i];
        float o[5];
        jet_eval(xv, W1, b1, W2, b2, W3, b3, W4, b4, o);
        float resid = o[4] + 1.0f;     // + P/(E*I) = 1
        acc = fmaf(resid, resid, acc);
    }

    // deterministic block reduction
    double a = (double)acc;
#pragma unroll
    for (int off = 32; off > 0; off >>= 1) a += __shfl_down(a, off, 64);
    __shared__ double red[4];
    int lane = tid & 63, wid = tid >> 6;
    if (lane == 0) red[wid] = a;
    __syncthreads();
    if (tid == 0) partials[blockIdx.x] = red[0] + red[1] + red[2] + red[3];
}

// ---- finish: reduce partials, boundary evals (per-lane, unrolled), scalars --
__global__ void __launch_bounds__(256)
pinn_finish(const double* __restrict__ partials, int nparts,
            const float* __restrict__ W1, const float* __restrict__ b1,
            const float* __restrict__ W2, const float* __restrict__ b2,
            const float* __restrict__ W3, const float* __restrict__ b3,
            const float* __restrict__ W4, const float* __restrict__ b4,
            float* __restrict__ out, int N, float* __restrict__ consts) {
    int tid = threadIdx.x;
    double a = 0.0;
    for (int i = tid; i < nparts; i += 256) a += partials[i];
#pragma unroll
    for (int off = 32; off > 0; off >>= 1) a += __shfl_down(a, off, 64);
    __shared__ double red[4];
    if ((tid & 63) == 0) red[tid >> 6] = a;
    __syncthreads();

    // wave 0 evaluates boundary jets (even lanes x=0, odd lanes x=1)
    __shared__ float jsh[2][5];
    if (tid < 64) {
        float xv = (tid & 1) ? 1.0f : 0.0f;
        float o[5];
        jet_eval(xv, W1, b1, W2, b2, W3, b3, W4, b4, o);
        if (tid < 2) {
#pragma unroll
            for (int c = 0; c < 5; ++c) jsh[tid][c] = o[c];
        }
    }
    __syncthreads();
    if (tid == 0) {
        double total = red[0] + red[1] + red[2] + red[3];
        float pdef = (float)(total / (double)N);
        float lbw  = jsh[0][0] * jsh[0][0];
        float lbwx = jsh[0][1] * jsh[0][1];
        float rbM  = jsh[1][2] * jsh[1][2];
        float rbw  = jsh[1][0] * jsh[1][0];
        float loss = pdef + lbw + lbwx + rbM + rbw;  // reference add order
        consts[0] = loss; consts[1] = lbw; consts[2] = lbwx;
        consts[3] = rbM;  consts[4] = rbw;
        out[N] = pdef;   // pde_loss scalar
    }
}

// ---- fill: broadcast 5 constants into their [N] regions ---------------------
__global__ void __launch_bounds__(256)
pinn_fill(float* __restrict__ out, const float* __restrict__ consts, int N) {
    int r = blockIdx.y;                       // 0:loss 1:lbw 2:lbwx 3:rbM 4:rbw
    float c = consts[r];
    size_t base = (r == 0) ? 0 : ((size_t)r * (size_t)N + 1);
    float* p = out + base;
    size_t tid = (size_t)blockIdx.x * blockDim.x + threadIdx.x;
    size_t stride = (size_t)gridDim.x * blockDim.x;
    size_t head = ((16 - ((size_t)p & 15)) & 15) >> 2;  // floats to 16B align
    size_t n = (size_t)N;
    if (head > n) head = n;
    if (tid < head) p[tid] = c;
    size_t n4 = (n - head) >> 2;
    float4* p4 = reinterpret_cast<float4*>(p + head);
    float4 cv = {c, c, c, c};
    for (size_t i = tid; i < n4; i += stride) p4[i] = cv;
    size_t done = head + (n4 << 2);
    size_t t = done + tid;
    if (t < n) p[t] = c;
}

extern "C" void kernel_launch(void* const* d_in, const int* in_sizes, int n_in,
                              void* d_out, int out_size, void* d_ws, size_t ws_size,
                              hipStream_t stream) {
    const float* x  = (const float*)d_in[0];
    const float* W1 = (const float*)d_in[1];
    const float* b1 = (const float*)d_in[2];
    const float* W2 = (const float*)d_in[3];
    const float* b2 = (const float*)d_in[4];
    const float* W3 = (const float*)d_in[5];
    const float* b3 = (const float*)d_in[6];
    const float* W4 = (const float*)d_in[7];
    const float* b4 = (const float*)d_in[8];
    float* out = (float*)d_out;
    int N = in_sizes[0];

    float* consts = (float*)d_ws;                       // 8 floats @ offset 0
    double* partials = (double*)((char*)d_ws + 256);    // NB doubles @ 256

    int NB = 2048;
    size_t need = 256 + (size_t)NB * 8;
    if (ws_size < need) {
        NB = (int)((ws_size > 256 + 8) ? (ws_size - 256) / 8 : 1);
        if (NB < 1) NB = 1;
        if (NB > 2048) NB = 2048;
    }

    hipLaunchKernelGGL(pinn_main, dim3(NB), dim3(256), 0, stream,
                       x, W1, b1, W2, b2, W3, b3, W4, b4, partials, N);
    hipLaunchKernelGGL(pinn_finish, dim3(1), dim3(256), 0, stream,
                       partials, NB, W1, b1, W2, b2, W3, b3, W4, b4,
                       out, N, consts);
    int gx = (N / 4 + 255) / 256;
    if (gx > 1024) gx = 1024;
    if (gx < 1) gx = 1;
    hipLaunchKernelGGL(pinn_fill, dim3(gx, 5), dim3(256), 0, stream,
                       out, consts, N);
}

// Round 4
// 539.004 us; speedup vs baseline: 1.3368x; 1.3368x over previous
//
#include <hip/hip_runtime.h>

#define DH 15

// ---- stable tanh + derivative factors -------------------------------------
// t = tanh(u), s = sech^2(u), f2 = t'', f3 = t''', f4 = t''''
__device__ __forceinline__ void tanh_fs(float u0, float& t, float& s,
                                        float& f2, float& f3, float& f4) {
    float e = __builtin_amdgcn_exp2f(u0 * 2.885390081777927f); // exp(2*u0)
    float r = __builtin_amdgcn_rcpf(1.0f + e);
    t = 1.0f - 2.0f * r;
    s = 4.0f * r * (1.0f - r);           // no inf*0, no cancellation
    f2 = -2.0f * t * s;
    f3 = s * (4.0f * t * t - 2.0f * s);
    f4 = 8.0f * t * s * (2.0f * s - t * t);
}

// degree-4 jet composition h = tanh(u) (Faà di Bruno)
__device__ __forceinline__ void tanh_jet(float u0, float u1, float u2,
                                         float u3, float u4, float h[5]) {
    float t, s, f2, f3, f4;
    tanh_fs(u0, t, s, f2, f3, f4);
    float u1s = u1 * u1;
    h[0] = t;
    h[1] = s * u1;
    h[2] = f2 * u1s + s * u2;
    h[3] = f3 * u1s * u1 + 3.0f * f2 * u1 * u2 + s * u3;
    h[4] = f4 * u1s * u1s + 6.0f * f3 * u1s * u2
         + f2 * (3.0f * u2 * u2 + 4.0f * u1 * u3) + s * u4;
}

// dense 15->15 + tanh on jets. Weights/biases read with wave-uniform
// compile-time-constant addresses -> s_load into SGPRs; v_fmac takes the
// SGPR as one source. No weight VGPRs, no LDS, no copy movs.
// sched_barrier(0) per row bounds VGPR temp live-ranges and s_load hoisting.
__device__ __forceinline__ void dense_tanh(float h[DH][5],
                                           const float* __restrict__ W,
                                           const float* __restrict__ B) {
    float u[DH][5];
    {   // k = 0 peeled: fold init into FMAs (no zero-movs)
        float h0 = h[0][0], h1 = h[0][1], h2 = h[0][2], h3 = h[0][3], h4 = h[0][4];
#pragma unroll
        for (int j = 0; j < DH; ++j) {
            float w = W[j];
            u[j][0] = fmaf(h0, w, B[j]);
            u[j][1] = h1 * w;
            u[j][2] = h2 * w;
            u[j][3] = h3 * w;
            u[j][4] = h4 * w;
        }
        __builtin_amdgcn_sched_barrier(0);
    }
#pragma unroll
    for (int k = 1; k < DH; ++k) {
        float h0 = h[k][0], h1 = h[k][1], h2 = h[k][2], h3 = h[k][3], h4 = h[k][4];
#pragma unroll
        for (int j = 0; j < DH; ++j) {
            float w = W[k * DH + j];
            u[j][0] = fmaf(h0, w, u[j][0]);
            u[j][1] = fmaf(h1, w, u[j][1]);
            u[j][2] = fmaf(h2, w, u[j][2]);
            u[j][3] = fmaf(h3, w, u[j][3]);
            u[j][4] = fmaf(h4, w, u[j][4]);
        }
        __builtin_amdgcn_sched_barrier(0);
    }
#pragma unroll
    for (int j = 0; j < DH; ++j) {
        float hj[5];
        tanh_jet(u[j][0], u[j][1], u[j][2], u[j][3], u[j][4], hj);
        h[j][0] = hj[0]; h[j][1] = hj[1]; h[j][2] = hj[2];
        h[j][3] = hj[3]; h[j][4] = hj[4];
        __builtin_amdgcn_sched_barrier(0);
    }
}

// full degree-4 jet through the MLP for one scalar x (SGPR weights)
__device__ __forceinline__ void jet_eval(float xv,
                                         const float* __restrict__ W1,
                                         const float* __restrict__ b1,
                                         const float* __restrict__ W2,
                                         const float* __restrict__ b2,
                                         const float* __restrict__ W3,
                                         const float* __restrict__ b3,
                                         const float* __restrict__ W4,
                                         const float* __restrict__ b4,
                                         float o[5]) {
    float h[DH][5];
#pragma unroll
    for (int j = 0; j < DH; ++j) {
        float w = W1[j];
        float t, s, f2, f3, f4;
        tanh_fs(fmaf(xv, w, b1[j]), t, s, f2, f3, f4);
        float w2 = w * w;
        h[j][0] = t;
        h[j][1] = s * w;
        h[j][2] = f2 * w2;
        h[j][3] = f3 * w2 * w;
        h[j][4] = f4 * w2 * w2;
        __builtin_amdgcn_sched_barrier(0);
    }
    dense_tanh(h, W2, b2);
    dense_tanh(h, W3, b3);
    float o0 = b4[0], o1 = 0.f, o2 = 0.f, o3 = 0.f, o4 = 0.f;
#pragma unroll
    for (int k = 0; k < DH; ++k) {
        float w = W4[k];
        o0 = fmaf(h[k][0], w, o0);
        o1 = fmaf(h[k][1], w, o1);
        o2 = fmaf(h[k][2], w, o2);
        o3 = fmaf(h[k][3], w, o3);
        o4 = fmaf(h[k][4], w, o4);
    }
    o[0] = o0; o[1] = o1; o[2] = o2; o[3] = o3; o[4] = o4;
}

// ---- main kernel: per-point degree-4 jet, reduce (w''''+1)^2 ----------------
// No min-wave clause: round 3 showed forcing 3 waves/SIMD (~170 VGPR cap)
// collapses the allocator into a scratch-spill cascade (VGPR=84, 1.4 GB
// scratch traffic). Let it take ~2 waves/SIMD spill-free.
__global__ void __launch_bounds__(256)
pinn_main(const float* __restrict__ x,
          const float* __restrict__ W1, const float* __restrict__ b1,
          const float* __restrict__ W2, const float* __restrict__ b2,
          const float* __restrict__ W3, const float* __restrict__ b3,
          const float* __restrict__ W4, const float* __restrict__ b4,
          double* __restrict__ partials, int N) {
    int tid = threadIdx.x;
    float acc = 0.0f;
    int idx0 = blockIdx.x * blockDim.x + tid;
    int gsz = gridDim.x * blockDim.x;
    for (int i = idx0; i < N; i += gsz) {
        float xv = x[i];
        float o[5];
        jet_eval(xv, W1, b1, W2, b2, W3, b3, W4, b4, o);
        float resid = o[4] + 1.0f;     // + P/(E*I) = 1
        acc = fmaf(resid, resid, acc);
    }

    // deterministic block reduction
    double a = (double)acc;
#pragma unroll
    for (int off = 32; off > 0; off >>= 1) a += __shfl_down(a, off, 64);
    __shared__ double red[4];
    int lane = tid & 63, wid = tid >> 6;
    if (lane == 0) red[wid] = a;
    __syncthreads();
    if (tid == 0) partials[blockIdx.x] = red[0] + red[1] + red[2] + red[3];
}

// ---- finish: reduce partials, boundary evals (per-lane, unrolled), scalars --
__global__ void __launch_bounds__(256)
pinn_finish(const double* __restrict__ partials, int nparts,
            const float* __restrict__ W1, const float* __restrict__ b1,
            const float* __restrict__ W2, const float* __restrict__ b2,
            const float* __restrict__ W3, const float* __restrict__ b3,
            const float* __restrict__ W4, const float* __restrict__ b4,
            float* __restrict__ out, int N, float* __restrict__ consts) {
    int tid = threadIdx.x;
    double a = 0.0;
    for (int i = tid; i < nparts; i += 256) a += partials[i];
#pragma unroll
    for (int off = 32; off > 0; off >>= 1) a += __shfl_down(a, off, 64);
    __shared__ double red[4];
    if ((tid & 63) == 0) red[tid >> 6] = a;
    __syncthreads();

    // wave 0 evaluates boundary jets (even lanes x=0, odd lanes x=1)
    __shared__ float jsh[2][5];
    if (tid < 64) {
        float xv = (tid & 1) ? 1.0f : 0.0f;
        float o[5];
        jet_eval(xv, W1, b1, W2, b2, W3, b3, W4, b4, o);
        if (tid < 2) {
#pragma unroll
            for (int c = 0; c < 5; ++c) jsh[tid][c] = o[c];
        }
    }
    __syncthreads();
    if (tid == 0) {
        double total = red[0] + red[1] + red[2] + red[3];
        float pdef = (float)(total / (double)N);
        float lbw  = jsh[0][0] * jsh[0][0];
        float lbwx = jsh[0][1] * jsh[0][1];
        float rbM  = jsh[1][2] * jsh[1][2];
        float rbw  = jsh[1][0] * jsh[1][0];
        float loss = pdef + lbw + lbwx + rbM + rbw;  // reference add order
        consts[0] = loss; consts[1] = lbw; consts[2] = lbwx;
        consts[3] = rbM;  consts[4] = rbw;
        out[N] = pdef;   // pde_loss scalar
    }
}

// ---- fill: broadcast 5 constants into their [N] regions ---------------------
__global__ void __launch_bounds__(256)
pinn_fill(float* __restrict__ out, const float* __restrict__ consts, int N) {
    int r = blockIdx.y;                       // 0:loss 1:lbw 2:lbwx 3:rbM 4:rbw
    float c = consts[r];
    size_t base = (r == 0) ? 0 : ((size_t)r * (size_t)N + 1);
    float* p = out + base;
    size_t tid = (size_t)blockIdx.x * blockDim.x + threadIdx.x;
    size_t stride = (size_t)gridDim.x * blockDim.x;
    size_t head = ((16 - ((size_t)p & 15)) & 15) >> 2;  // floats to 16B align
    size_t n = (size_t)N;
    if (head > n) head = n;
    if (tid < head) p[tid] = c;
    size_t n4 = (n - head) >> 2;
    float4* p4 = reinterpret_cast<float4*>(p + head);
    float4 cv = {c, c, c, c};
    for (size_t i = tid; i < n4; i += stride) p4[i] = cv;
    size_t done = head + (n4 << 2);
    size_t t = done + tid;
    if (t < n) p[t] = c;
}

extern "C" void kernel_launch(void* const* d_in, const int* in_sizes, int n_in,
                              void* d_out, int out_size, void* d_ws, size_t ws_size,
                              hipStream_t stream) {
    const float* x  = (const float*)d_in[0];
    const float* W1 = (const float*)d_in[1];
    const float* b1 = (const float*)d_in[2];
    const float* W2 = (const float*)d_in[3];
    const float* b2 = (const float*)d_in[4];
    const float* W3 = (const float*)d_in[5];
    const float* b3 = (const float*)d_in[6];
    const float* W4 = (const float*)d_in[7];
    const float* b4 = (const float*)d_in[8];
    float* out = (float*)d_out;
    int N = in_sizes[0];

    float* consts = (float*)d_ws;                       // 8 floats @ offset 0
    double* partials = (double*)((char*)d_ws + 256);    // NB doubles @ 256

    int NB = 2048;
    size_t need = 256 + (size_t)NB * 8;
    if (ws_size < need) {
        NB = (int)((ws_size > 256 + 8) ? (ws_size - 256) / 8 : 1);
        if (NB < 1) NB = 1;
        if (NB > 2048) NB = 2048;
    }

    hipLaunchKernelGGL(pinn_main, dim3(NB), dim3(256), 0, stream,
                       x, W1, b1, W2, b2, W3, b3, W4, b4, partials, N);
    hipLaunchKernelGGL(pinn_finish, dim3(1), dim3(256), 0, stream,
                       partials, NB, W1, b1, W2, b2, W3, b3, W4, b4,
                       out, N, consts);
    int gx = (N / 4 + 255) / 256;
    if (gx > 1024) gx = 1024;
    if (gx < 1) gx = 1;
    hipLaunchKernelGGL(pinn_fill, dim3(gx, 5), dim3(256), 0, stream,
                       out, consts, N);
}

// Round 5
// 226.877 us; speedup vs baseline: 3.1758x; 2.3757x over previous
//
#include <hip/hip_runtime.h>

#define DH 15

typedef float v2f __attribute__((ext_vector_type(2)));

// ---- stable tanh + derivative factors -------------------------------------
// t = tanh(u), s = sech^2(u), f2 = t'', f3 = t''', f4 = t''''
__device__ __forceinline__ void tanh_fs(float u0, float& t, float& s,
                                        float& f2, float& f3, float& f4) {
    float e = __builtin_amdgcn_exp2f(u0 * 2.885390081777927f); // exp(2*u0)
    float r = __builtin_amdgcn_rcpf(1.0f + e);
    t = 1.0f - 2.0f * r;
    s = 4.0f * r * (1.0f - r);           // no inf*0, no cancellation
    f2 = -2.0f * t * s;
    f3 = s * (4.0f * t * t - 2.0f * s);
    f4 = 8.0f * t * s * (2.0f * s - t * t);
}

// degree-4 jet composition h = tanh(u) (Faà di Bruno)
__device__ __forceinline__ void tanh_jet(float u0, float u1, float u2,
                                         float u3, float u4, float h[5]) {
    float t, s, f2, f3, f4;
    tanh_fs(u0, t, s, f2, f3, f4);
    float u1s = u1 * u1;
    h[0] = t;
    h[1] = s * u1;
    h[2] = f2 * u1s + s * u2;
    h[3] = f3 * u1s * u1 + 3.0f * f2 * u1 * u2 + s * u3;
    h[4] = f4 * u1s * u1s + 6.0f * f3 * u1s * u2
         + f2 * (3.0f * u2 * u2 + 4.0f * u1 * u3) + s * u4;
}

// one dense row k: U[c][p] (+)= splat(h_c) * w_pair[p], packed across j-pairs.
// Weight pairs alias the float4 quad registers (even-aligned) -> no movs.
template <bool FIRST>
__device__ __forceinline__ void row_fma(v2f U[5][8],
                                        float h0, float h1, float h2, float h3,
                                        float h4, float4 q0, float4 q1,
                                        float4 q2, float4 q3) {
    v2f s0 = {h0, h0}, s1 = {h1, h1}, s2 = {h2, h2}, s3 = {h3, h3}, s4 = {h4, h4};
    v2f wp[8] = {{q0.x, q0.y}, {q0.z, q0.w}, {q1.x, q1.y}, {q1.z, q1.w},
                 {q2.x, q2.y}, {q2.z, q2.w}, {q3.x, q3.y}, {q3.z, q3.w}};
#pragma unroll
    for (int p = 0; p < 8; ++p) {
        if (FIRST) {
            U[0][p] = s0 * wp[p];
            U[1][p] = s1 * wp[p];
            U[2][p] = s2 * wp[p];
            U[3][p] = s3 * wp[p];
            U[4][p] = s4 * wp[p];
        } else {
            U[0][p] = __builtin_elementwise_fma(s0, wp[p], U[0][p]);
            U[1][p] = __builtin_elementwise_fma(s1, wp[p], U[1][p]);
            U[2][p] = __builtin_elementwise_fma(s2, wp[p], U[2][p]);
            U[3][p] = __builtin_elementwise_fma(s3, wp[p], U[3][p]);
            U[4][p] = __builtin_elementwise_fma(s4, wp[p], U[4][p]);
        }
    }
}

// dense 15->15 + tanh on jets. Weights in LDS as [15][4] float4 (row pad = 0),
// copy-free parity ping-pong prefetch; bias (global-uniform -> SGPR) added at
// the end, scalar. sched_barrier(0) per row bounds prefetch distance to 1 row.
__device__ __forceinline__ void dense_pk(float h[DH][5],
                                         const float4* __restrict__ rp,
                                         const float* __restrict__ Bg) {
    v2f U[5][8];
    float4 a0 = rp[0], a1 = rp[1], a2 = rp[2], a3 = rp[3];
    float4 b0 = rp[4], b1 = rp[5], b2 = rp[6], b3 = rp[7];
    row_fma<true>(U, h[0][0], h[0][1], h[0][2], h[0][3], h[0][4], a0, a1, a2, a3);
    __builtin_amdgcn_sched_barrier(0);
#pragma unroll
    for (int k = 1; k < DH; k += 2) {
        if (k + 1 < DH) {
            a0 = rp[4 * k + 4]; a1 = rp[4 * k + 5];
            a2 = rp[4 * k + 6]; a3 = rp[4 * k + 7];
        }
        row_fma<false>(U, h[k][0], h[k][1], h[k][2], h[k][3], h[k][4],
                       b0, b1, b2, b3);
        __builtin_amdgcn_sched_barrier(0);
        if (k + 1 < DH) {
            if (k + 2 < DH) {
                b0 = rp[4 * k + 8]; b1 = rp[4 * k + 9];
                b2 = rp[4 * k + 10]; b3 = rp[4 * k + 11];
            }
            row_fma<false>(U, h[k + 1][0], h[k + 1][1], h[k + 1][2],
                           h[k + 1][3], h[k + 1][4], a0, a1, a2, a3);
            __builtin_amdgcn_sched_barrier(0);
        }
    }
    // bias + tanh jets; barrier window = 3 neurons (lets exp/rcp chains overlap)
#pragma unroll
    for (int j = 0; j < DH; ++j) {
        const int p = j >> 1, e = j & 1;
        float u0 = (e ? U[0][p].y : U[0][p].x) + Bg[j];
        float u1 = e ? U[1][p].y : U[1][p].x;
        float u2 = e ? U[2][p].y : U[2][p].x;
        float u3 = e ? U[3][p].y : U[3][p].x;
        float u4 = e ? U[4][p].y : U[4][p].x;
        float hj[5];
        tanh_jet(u0, u1, u2, u3, u4, hj);
        h[j][0] = hj[0]; h[j][1] = hj[1]; h[j][2] = hj[2];
        h[j][3] = hj[3]; h[j][4] = hj[4];
        if ((j % 3) == 2) __builtin_amdgcn_sched_barrier(0);
    }
}

// ---- main kernel: per-point degree-4 jet, reduce (w''''+1)^2 ----------------
__global__ void __launch_bounds__(256)
pinn_main(const float* __restrict__ x,
          const float* __restrict__ W1, const float* __restrict__ b1,
          const float* __restrict__ W2, const float* __restrict__ b2,
          const float* __restrict__ W3, const float* __restrict__ b3,
          const float* __restrict__ W4, const float* __restrict__ b4,
          double* __restrict__ partials, int N) {
    __shared__ float4 sW2v[DH][4];
    __shared__ float4 sW3v[DH][4];
    {
        int t_ = threadIdx.x;
        if (t_ < DH * DH) {
            int k_ = t_ / DH, j_ = t_ % DH;
            ((float*)sW2v)[k_ * 16 + j_] = W2[t_];
            ((float*)sW3v)[k_ * 16 + j_] = W3[t_];
        }
        if (t_ < DH) {
            ((float*)sW2v)[t_ * 16 + 15] = 0.f;
            ((float*)sW3v)[t_ * 16 + 15] = 0.f;
        }
        __syncthreads();
    }

    int tid = threadIdx.x;
    float acc = 0.0f;
    int idx0 = blockIdx.x * blockDim.x + tid;
    int gsz = gridDim.x * blockDim.x;
    for (int i = idx0; i < N; i += gsz) {
        float xv = x[i];
        float h[DH][5];
        // layer 1 (scalar; W1/b1 are wave-uniform -> SGPR)
#pragma unroll
        for (int j = 0; j < DH; ++j) {
            float w = W1[j];
            float t, s, f2, f3, f4;
            tanh_fs(fmaf(xv, w, b1[j]), t, s, f2, f3, f4);
            float w2 = w * w;
            h[j][0] = t;
            h[j][1] = s * w;
            h[j][2] = f2 * w2;
            h[j][3] = f3 * w2 * w;
            h[j][4] = f4 * w2 * w2;
            if ((j % 3) == 2) __builtin_amdgcn_sched_barrier(0);
        }
        dense_pk(h, &sW2v[0][0], b2);
        dense_pk(h, &sW3v[0][0], b3);
        // output layer: only comp 4 (w'''') needed for the PDE residual;
        // DCE trims the last layer's unused h0..h3 jet math.
        float o4 = 0.f;
#pragma unroll
        for (int k = 0; k < DH; ++k) o4 = fmaf(h[k][4], W4[k], o4);
        float resid = o4 + 1.0f;       // + P/(E*I) = 1
        acc = fmaf(resid, resid, acc);
    }

    // deterministic block reduction
    double a = (double)acc;
#pragma unroll
    for (int off = 32; off > 0; off >>= 1) a += __shfl_down(a, off, 64);
    __shared__ double red[4];
    int lane = tid & 63, wid = tid >> 6;
    if (lane == 0) red[wid] = a;
    __syncthreads();
    if (tid == 0) partials[blockIdx.x] = red[0] + red[1] + red[2] + red[3];
}

// ---- scalar jet path for the tiny finish kernel (round-4 style) -------------
__device__ __forceinline__ void dense_tanh_s(float h[DH][5],
                                             const float* __restrict__ W,
                                             const float* __restrict__ B) {
    float u[DH][5];
    {
        float h0 = h[0][0], h1 = h[0][1], h2 = h[0][2], h3 = h[0][3], h4 = h[0][4];
#pragma unroll
        for (int j = 0; j < DH; ++j) {
            float w = W[j];
            u[j][0] = fmaf(h0, w, B[j]);
            u[j][1] = h1 * w; u[j][2] = h2 * w; u[j][3] = h3 * w; u[j][4] = h4 * w;
        }
        __builtin_amdgcn_sched_barrier(0);
    }
#pragma unroll
    for (int k = 1; k < DH; ++k) {
        float h0 = h[k][0], h1 = h[k][1], h2 = h[k][2], h3 = h[k][3], h4 = h[k][4];
#pragma unroll
        for (int j = 0; j < DH; ++j) {
            float w = W[k * DH + j];
            u[j][0] = fmaf(h0, w, u[j][0]);
            u[j][1] = fmaf(h1, w, u[j][1]);
            u[j][2] = fmaf(h2, w, u[j][2]);
            u[j][3] = fmaf(h3, w, u[j][3]);
            u[j][4] = fmaf(h4, w, u[j][4]);
        }
        __builtin_amdgcn_sched_barrier(0);
    }
#pragma unroll
    for (int j = 0; j < DH; ++j) {
        float hj[5];
        tanh_jet(u[j][0], u[j][1], u[j][2], u[j][3], u[j][4], hj);
        h[j][0] = hj[0]; h[j][1] = hj[1]; h[j][2] = hj[2];
        h[j][3] = hj[3]; h[j][4] = hj[4];
        if ((j % 3) == 2) __builtin_amdgcn_sched_barrier(0);
    }
}

__device__ __forceinline__ void jet_eval_s(float xv,
                                           const float* __restrict__ W1,
                                           const float* __restrict__ b1,
                                           const float* __restrict__ W2,
                                           const float* __restrict__ b2,
                                           const float* __restrict__ W3,
                                           const float* __restrict__ b3,
                                           const float* __restrict__ W4,
                                           const float* __restrict__ b4,
                                           float o[5]) {
    float h[DH][5];
#pragma unroll
    for (int j = 0; j < DH; ++j) {
        float w = W1[j];
        float t, s, f2, f3, f4;
        tanh_fs(fmaf(xv, w, b1[j]), t, s, f2, f3, f4);
        float w2 = w * w;
        h[j][0] = t; h[j][1] = s * w; h[j][2] = f2 * w2;
        h[j][3] = f3 * w2 * w; h[j][4] = f4 * w2 * w2;
        if ((j % 3) == 2) __builtin_amdgcn_sched_barrier(0);
    }
    dense_tanh_s(h, W2, b2);
    dense_tanh_s(h, W3, b3);
    float o0 = b4[0], o1 = 0.f, o2 = 0.f, o3 = 0.f, o4 = 0.f;
#pragma unroll
    for (int k = 0; k < DH; ++k) {
        float w = W4[k];
        o0 = fmaf(h[k][0], w, o0);
        o1 = fmaf(h[k][1], w, o1);
        o2 = fmaf(h[k][2], w, o2);
        o3 = fmaf(h[k][3], w, o3);
        o4 = fmaf(h[k][4], w, o4);
    }
    o[0] = o0; o[1] = o1; o[2] = o2; o[3] = o3; o[4] = o4;
}

// ---- finish: reduce partials, boundary evals, write scalars -----------------
__global__ void __launch_bounds__(256)
pinn_finish(const double* __restrict__ partials, int nparts,
            const float* __restrict__ W1, const float* __restrict__ b1,
            const float* __restrict__ W2, const float* __restrict__ b2,
            const float* __restrict__ W3, const float* __restrict__ b3,
            const float* __restrict__ W4, const float* __restrict__ b4,
            float* __restrict__ out, int N, float* __restrict__ consts) {
    int tid = threadIdx.x;
    double a = 0.0;
    for (int i = tid; i < nparts; i += 256) a += partials[i];
#pragma unroll
    for (int off = 32; off > 0; off >>= 1) a += __shfl_down(a, off, 64);
    __shared__ double red[4];
    if ((tid & 63) == 0) red[tid >> 6] = a;
    __syncthreads();

    // wave 0 evaluates boundary jets (even lanes x=0, odd lanes x=1)
    __shared__ float jsh[2][5];
    if (tid < 64) {
        float xv = (tid & 1) ? 1.0f : 0.0f;
        float o[5];
        jet_eval_s(xv, W1, b1, W2, b2, W3, b3, W4, b4, o);
        if (tid < 2) {
#pragma unroll
            for (int c = 0; c < 5; ++c) jsh[tid][c] = o[c];
        }
    }
    __syncthreads();
    if (tid == 0) {
        double total = red[0] + red[1] + red[2] + red[3];
        float pdef = (float)(total / (double)N);
        float lbw  = jsh[0][0] * jsh[0][0];
        float lbwx = jsh[0][1] * jsh[0][1];
        float rbM  = jsh[1][2] * jsh[1][2];
        float rbw  = jsh[1][0] * jsh[1][0];
        float loss = pdef + lbw + lbwx + rbM + rbw;  // reference add order
        consts[0] = loss; consts[1] = lbw; consts[2] = lbwx;
        consts[3] = rbM;  consts[4] = rbw;
        out[N] = pdef;   // pde_loss scalar
    }
}

// ---- fill: broadcast 5 constants into their [N] regions ---------------------
__global__ void __launch_bounds__(256)
pinn_fill(float* __restrict__ out, const float* __restrict__ consts, int N) {
    int r = blockIdx.y;                       // 0:loss 1:lbw 2:lbwx 3:rbM 4:rbw
    float c = consts[r];
    size_t base = (r == 0) ? 0 : ((size_t)r * (size_t)N + 1);
    float* p = out + base;
    size_t tid = (size_t)blockIdx.x * blockDim.x + threadIdx.x;
    size_t stride = (size_t)gridDim.x * blockDim.x;
    size_t head = ((16 - ((size_t)p & 15)) & 15) >> 2;  // floats to 16B align
    size_t n = (size_t)N;
    if (head > n) head = n;
    if (tid < head) p[tid] = c;
    size_t n4 = (n - head) >> 2;
    float4* p4 = reinterpret_cast<float4*>(p + head);
    float4 cv = {c, c, c, c};
    for (size_t i = tid; i < n4; i += stride) p4[i] = cv;
    size_t done = head + (n4 << 2);
    size_t t = done + tid;
    if (t < n) p[t] = c;
}

extern "C" void kernel_launch(void* const* d_in, const int* in_sizes, int n_in,
                              void* d_out, int out_size, void* d_ws, size_t ws_size,
                              hipStream_t stream) {
    const float* x  = (const float*)d_in[0];
    const float* W1 = (const float*)d_in[1];
    const float* b1 = (const float*)d_in[2];
    const float* W2 = (const float*)d_in[3];
    const float* b2 = (const float*)d_in[4];
    const float* W3 = (const float*)d_in[5];
    const float* b3 = (const float*)d_in[6];
    const float* W4 = (const float*)d_in[7];
    const float* b4 = (const float*)d_in[8];
    float* out = (float*)d_out;
    int N = in_sizes[0];

    float* consts = (float*)d_ws;                       // 8 floats @ offset 0
    double* partials = (double*)((char*)d_ws + 256);    // NB doubles @ 256

    // 512 blocks = exactly 2 resident blocks/CU at ~2 waves/SIMD: no tail.
    int NB = 512;
    size_t need = 256 + (size_t)NB * 8;
    if (ws_size < need) {
        NB = (int)((ws_size > 256 + 8) ? (ws_size - 256) / 8 : 1);
        if (NB < 1) NB = 1;
        if (NB > 512) NB = 512;
    }

    hipLaunchKernelGGL(pinn_main, dim3(NB), dim3(256), 0, stream,
                       x, W1, b1, W2, b2, W3, b3, W4, b4, partials, N);
    hipLaunchKernelGGL(pinn_finish, dim3(1), dim3(256), 0, stream,
                       partials, NB, W1, b1, W2, b2, W3, b3, W4, b4,
                       out, N, consts);
    int gx = (N / 4 + 255) / 256;
    if (gx > 1024) gx = 1024;
    if (gx < 1) gx = 1;
    hipLaunchKernelGGL(pinn_fill, dim3(gx, 5), dim3(256), 0, stream,
                       out, consts, N);
}

// Round 6
// 56.592 us; speedup vs baseline: 12.7319x; 4.0090x over previous
//
#include <hip/hip_runtime.h>
#include <math.h>

#define DH 15
#define NNODES 64           // Chebyshev-Lobatto nodes, degree 63
#define M_DEG  63

typedef float v2f __attribute__((ext_vector_type(2)));

// ---- stable tanh + derivative factors -------------------------------------
__device__ __forceinline__ void tanh_fs(float u0, float& t, float& s,
                                        float& f2, float& f3, float& f4) {
    float e = __builtin_amdgcn_exp2f(u0 * 2.885390081777927f); // exp(2*u0)
    float r = __builtin_amdgcn_rcpf(1.0f + e);
    t = 1.0f - 2.0f * r;
    s = 4.0f * r * (1.0f - r);
    f2 = -2.0f * t * s;
    f3 = s * (4.0f * t * t - 2.0f * s);
    f4 = 8.0f * t * s * (2.0f * s - t * t);
}

__device__ __forceinline__ void tanh_jet(float u0, float u1, float u2,
                                         float u3, float u4, float h[5]) {
    float t, s, f2, f3, f4;
    tanh_fs(u0, t, s, f2, f3, f4);
    float u1s = u1 * u1;
    h[0] = t;
    h[1] = s * u1;
    h[2] = f2 * u1s + s * u2;
    h[3] = f3 * u1s * u1 + 3.0f * f2 * u1 * u2 + s * u3;
    h[4] = f4 * u1s * u1s + 6.0f * f3 * u1s * u2
         + f2 * (3.0f * u2 * u2 + 4.0f * u1 * u3) + s * u4;
}

// ---- exact degree-4 jet through the MLP (scalar path, known-good) ----------
__device__ __forceinline__ void dense_tanh_s(float h[DH][5],
                                             const float* __restrict__ W,
                                             const float* __restrict__ B) {
    float u[DH][5];
    {
        float h0 = h[0][0], h1 = h[0][1], h2 = h[0][2], h3 = h[0][3], h4 = h[0][4];
#pragma unroll
        for (int j = 0; j < DH; ++j) {
            float w = W[j];
            u[j][0] = fmaf(h0, w, B[j]);
            u[j][1] = h1 * w; u[j][2] = h2 * w; u[j][3] = h3 * w; u[j][4] = h4 * w;
        }
        __builtin_amdgcn_sched_barrier(0);
    }
#pragma unroll
    for (int k = 1; k < DH; ++k) {
        float h0 = h[k][0], h1 = h[k][1], h2 = h[k][2], h3 = h[k][3], h4 = h[k][4];
#pragma unroll
        for (int j = 0; j < DH; ++j) {
            float w = W[k * DH + j];
            u[j][0] = fmaf(h0, w, u[j][0]);
            u[j][1] = fmaf(h1, w, u[j][1]);
            u[j][2] = fmaf(h2, w, u[j][2]);
            u[j][3] = fmaf(h3, w, u[j][3]);
            u[j][4] = fmaf(h4, w, u[j][4]);
        }
        __builtin_amdgcn_sched_barrier(0);
    }
#pragma unroll
    for (int j = 0; j < DH; ++j) {
        float hj[5];
        tanh_jet(u[j][0], u[j][1], u[j][2], u[j][3], u[j][4], hj);
        h[j][0] = hj[0]; h[j][1] = hj[1]; h[j][2] = hj[2];
        h[j][3] = hj[3]; h[j][4] = hj[4];
        if ((j % 3) == 2) __builtin_amdgcn_sched_barrier(0);
    }
}

__device__ __forceinline__ void jet_eval_s(float xv,
                                           const float* __restrict__ W1,
                                           const float* __restrict__ b1,
                                           const float* __restrict__ W2,
                                           const float* __restrict__ b2,
                                           const float* __restrict__ W3,
                                           const float* __restrict__ b3,
                                           const float* __restrict__ W4,
                                           const float* __restrict__ b4,
                                           float o[5]) {
    float h[DH][5];
#pragma unroll
    for (int j = 0; j < DH; ++j) {
        float w = W1[j];
        float t, s, f2, f3, f4;
        tanh_fs(fmaf(xv, w, b1[j]), t, s, f2, f3, f4);
        float w2 = w * w;
        h[j][0] = t; h[j][1] = s * w; h[j][2] = f2 * w2;
        h[j][3] = f3 * w2 * w; h[j][4] = f4 * w2 * w2;
        if ((j % 3) == 2) __builtin_amdgcn_sched_barrier(0);
    }
    dense_tanh_s(h, W2, b2);
    dense_tanh_s(h, W3, b3);
    float o0 = b4[0], o1 = 0.f, o2 = 0.f, o3 = 0.f, o4 = 0.f;
#pragma unroll
    for (int k = 0; k < DH; ++k) {
        float w = W4[k];
        o0 = fmaf(h[k][0], w, o0);
        o1 = fmaf(h[k][1], w, o1);
        o2 = fmaf(h[k][2], w, o2);
        o3 = fmaf(h[k][3], w, o3);
        o4 = fmaf(h[k][4], w, o4);
    }
    o[0] = o0; o[1] = o1; o[2] = o2; o[3] = o3; o[4] = o4;
}

// ---- kernel A: exact jets at 64 Chebyshev-Lobatto nodes -> DCT-I coeffs -----
// lane j: x_j = (1+cos(pi*j/63))/2 (j=0 -> x=1, j=63 -> x=0; endpoints exact).
// Also stores the boundary jets (BC losses use the exact values).
__global__ void __launch_bounds__(64)
pinn_nodes(const float* __restrict__ W1, const float* __restrict__ b1,
           const float* __restrict__ W2, const float* __restrict__ b2,
           const float* __restrict__ W3, const float* __restrict__ b3,
           const float* __restrict__ W4, const float* __restrict__ b4,
           float* __restrict__ C, float* __restrict__ bc) {
    int j = threadIdx.x;           // 0..63
    float xv;
    if (j == 0)            xv = 1.0f;
    else if (j == M_DEG)   xv = 0.0f;
    else                   xv = 0.5f * (1.0f + cosf((float)(M_PI / 63.0) * (float)j));
    float o[5];
    jet_eval_s(xv, W1, b1, W2, b2, W3, b3, W4, b4, o);

    __shared__ float rsh[NNODES];
    rsh[j] = o[4] + 1.0f;          // PDE residual w'''' + P/(E*I)
    if (j == M_DEG) {              // x = 0 (left)
#pragma unroll
        for (int c = 0; c < 5; ++c) bc[c] = o[c];
    }
    if (j == 0) {                  // x = 1 (right)
#pragma unroll
        for (int c = 0; c < 5; ++c) bc[5 + c] = o[c];
    }
    __syncthreads();

    // DCT-I: c_k = (2/63) * sum'' r_j cos(pi*j*k/63); fold the series
    // end-halving into e_0, e_63 so r(t) = sum_k e_k T_k(t).
    int k = j;
    double s = 0.0;
    for (int jj = 0; jj < NNODES; ++jj) {
        int m = (jj * k) % 126;                       // exact periodic reduction
        float cv = cosf((float)(M_PI / 63.0) * (float)m);
        float wgt = (jj == 0 || jj == M_DEG) ? 0.5f : 1.0f;
        s += (double)(wgt * rsh[jj] * cv);
    }
    double e = s * (2.0 / 63.0);
    if (k == 0 || k == M_DEG) e *= 0.5;
    C[k] = (float)e;
}

// ---- kernel B: per-point Clenshaw (degree 63), reduce residual^2 ------------
__global__ void __launch_bounds__(256)
pinn_pde(const float* __restrict__ x, const float* __restrict__ Cc,
         double* __restrict__ partials, int N) {
    // coefficients: wave-uniform loads with compile-time indices -> SGPRs
    float e[NNODES];
#pragma unroll
    for (int k = 0; k < NNODES; ++k) e[k] = Cc[k];

    int tid = threadIdx.x;
    v2f accA = {0.f, 0.f}, accB = {0.f, 0.f};
    int i0 = blockIdx.x * blockDim.x + tid;
    int gsz = gridDim.x * blockDim.x;
    int n4 = N >> 2;
    const float4* x4 = reinterpret_cast<const float4*>(x);
    for (int i = i0; i < n4; i += gsz) {
        float4 xv = x4[i];
        v2f tA = {2.f * xv.x - 1.f, 2.f * xv.y - 1.f};
        v2f tB = {2.f * xv.z - 1.f, 2.f * xv.w - 1.f};
        v2f t2A = tA + tA, t2B = tB + tB;
        v2f b0A = {0.f, 0.f}, b1A = {0.f, 0.f};
        v2f b0B = {0.f, 0.f}, b1B = {0.f, 0.f};
#pragma unroll
        for (int k = M_DEG; k >= 1; --k) {
            v2f ek = {e[k], e[k]};
            v2f bnA = __builtin_elementwise_fma(t2A, b0A, ek) - b1A;
            b1A = b0A; b0A = bnA;
            v2f bnB = __builtin_elementwise_fma(t2B, b0B, ek) - b1B;
            b1B = b0B; b0B = bnB;
        }
        v2f e0 = {e[0], e[0]};
        v2f rA = __builtin_elementwise_fma(tA, b0A, e0) - b1A;
        v2f rB = __builtin_elementwise_fma(tB, b0B, e0) - b1B;
        accA = __builtin_elementwise_fma(rA, rA, accA);
        accB = __builtin_elementwise_fma(rB, rB, accB);
    }
    float accs = (accA.x + accA.y) + (accB.x + accB.y);
    // scalar tail (N % 4 != 0)
    for (int i = (n4 << 2) + i0; i < N; i += gsz) {
        float t = 2.f * x[i] - 1.f, t2 = t + t;
        float b0 = 0.f, b1 = 0.f;
#pragma unroll
        for (int k = M_DEG; k >= 1; --k) {
            float bn = fmaf(t2, b0, e[k]) - b1;
            b1 = b0; b0 = bn;
        }
        float r = fmaf(t, b0, e[0]) - b1;
        accs = fmaf(r, r, accs);
    }

    double a = (double)accs;
#pragma unroll
    for (int off = 32; off > 0; off >>= 1) a += __shfl_down(a, off, 64);
    __shared__ double red[4];
    int lane = tid & 63, wid = tid >> 6;
    if (lane == 0) red[wid] = a;
    __syncthreads();
    if (tid == 0) partials[blockIdx.x] = red[0] + red[1] + red[2] + red[3];
}

// ---- finish: reduce partials, combine with BC jets, write scalars -----------
__global__ void __launch_bounds__(256)
pinn_finish(const double* __restrict__ partials, int nparts,
            const float* __restrict__ bc,
            float* __restrict__ out, int N, float* __restrict__ consts) {
    int tid = threadIdx.x;
    double a = 0.0;
    for (int i = tid; i < nparts; i += 256) a += partials[i];
#pragma unroll
    for (int off = 32; off > 0; off >>= 1) a += __shfl_down(a, off, 64);
    __shared__ double red[4];
    if ((tid & 63) == 0) red[tid >> 6] = a;
    __syncthreads();
    if (tid == 0) {
        double total = red[0] + red[1] + red[2] + red[3];
        float pdef = (float)(total / (double)N);
        float lbw  = bc[0] * bc[0];   // w(0)^2
        float lbwx = bc[1] * bc[1];   // w_x(0)^2
        float rbM  = bc[7] * bc[7];   // w_xx(1)^2
        float rbw  = bc[5] * bc[5];   // w(1)^2
        float loss = pdef + lbw + lbwx + rbM + rbw;  // reference add order
        consts[0] = loss; consts[1] = lbw; consts[2] = lbwx;
        consts[3] = rbM;  consts[4] = rbw;
        out[N] = pdef;   // pde_loss scalar
    }
}

// ---- fill: broadcast 5 constants into their [N] regions ---------------------
__global__ void __launch_bounds__(256)
pinn_fill(float* __restrict__ out, const float* __restrict__ consts, int N) {
    int r = blockIdx.y;                       // 0:loss 1:lbw 2:lbwx 3:rbM 4:rbw
    float c = consts[r];
    size_t base = (r == 0) ? 0 : ((size_t)r * (size_t)N + 1);
    float* p = out + base;
    size_t tid = (size_t)blockIdx.x * blockDim.x + threadIdx.x;
    size_t stride = (size_t)gridDim.x * blockDim.x;
    size_t head = ((16 - ((size_t)p & 15)) & 15) >> 2;  // floats to 16B align
    size_t n = (size_t)N;
    if (head > n) head = n;
    if (tid < head) p[tid] = c;
    size_t n4 = (n - head) >> 2;
    float4* p4 = reinterpret_cast<float4*>(p + head);
    float4 cv = {c, c, c, c};
    for (size_t i = tid; i < n4; i += stride) p4[i] = cv;
    size_t done = head + (n4 << 2);
    size_t t = done + tid;
    if (t < n) p[t] = c;
}

extern "C" void kernel_launch(void* const* d_in, const int* in_sizes, int n_in,
                              void* d_out, int out_size, void* d_ws, size_t ws_size,
                              hipStream_t stream) {
    const float* x  = (const float*)d_in[0];
    const float* W1 = (const float*)d_in[1];
    const float* b1 = (const float*)d_in[2];
    const float* W2 = (const float*)d_in[3];
    const float* b2 = (const float*)d_in[4];
    const float* W3 = (const float*)d_in[5];
    const float* b3 = (const float*)d_in[6];
    const float* W4 = (const float*)d_in[7];
    const float* b4 = (const float*)d_in[8];
    float* out = (float*)d_out;
    int N = in_sizes[0];

    // ws layout: C[64] @0 | bc[10] @256B | consts[8] @384B | partials @1024B
    float*  C        = (float*)d_ws;
    float*  bc       = (float*)((char*)d_ws + 256);
    float*  consts   = (float*)((char*)d_ws + 384);
    double* partials = (double*)((char*)d_ws + 1024);

    int NB = 512;
    size_t need = 1024 + (size_t)NB * 8;
    if (ws_size < need) {
        NB = (int)((ws_size > 1024 + 8) ? (ws_size - 1024) / 8 : 1);
        if (NB < 1) NB = 1;
        if (NB > 512) NB = 512;
    }

    hipLaunchKernelGGL(pinn_nodes, dim3(1), dim3(64), 0, stream,
                       W1, b1, W2, b2, W3, b3, W4, b4, C, bc);
    hipLaunchKernelGGL(pinn_pde, dim3(NB), dim3(256), 0, stream,
                       x, C, partials, N);
    hipLaunchKernelGGL(pinn_finish, dim3(1), dim3(256), 0, stream,
                       partials, NB, bc, out, N, consts);
    int gx = (N / 4 + 255) / 256;
    if (gx > 1024) gx = 1024;
    if (gx < 1) gx = 1;
    hipLaunchKernelGGL(pinn_fill, dim3(gx, 5), dim3(256), 0, stream,
                       out, consts, N);
}

// Round 7
// 47.137 us; speedup vs baseline: 15.2856x; 1.2006x over previous
//
#include <hip/hip_runtime.h>
#include <math.h>

#define DH 15
#define NNODES 64           // Chebyshev-Lobatto nodes, degree 63
#define M_DEG  63

typedef float v2f __attribute__((ext_vector_type(2)));

// ---- stable tanh + derivative factors -------------------------------------
__device__ __forceinline__ void tanh_fs(float u0, float& t, float& s,
                                        float& f2, float& f3, float& f4) {
    float e = __builtin_amdgcn_exp2f(u0 * 2.885390081777927f); // exp(2*u0)
    float r = __builtin_amdgcn_rcpf(1.0f + e);
    t = 1.0f - 2.0f * r;
    s = 4.0f * r * (1.0f - r);
    f2 = -2.0f * t * s;
    f3 = s * (4.0f * t * t - 2.0f * s);
    f4 = 8.0f * t * s * (2.0f * s - t * t);
}

__device__ __forceinline__ void tanh_jet(float u0, float u1, float u2,
                                         float u3, float u4, float h[5]) {
    float t, s, f2, f3, f4;
    tanh_fs(u0, t, s, f2, f3, f4);
    float u1s = u1 * u1;
    h[0] = t;
    h[1] = s * u1;
    h[2] = f2 * u1s + s * u2;
    h[3] = f3 * u1s * u1 + 3.0f * f2 * u1 * u2 + s * u3;
    h[4] = f4 * u1s * u1s + 6.0f * f3 * u1s * u2
         + f2 * (3.0f * u2 * u2 + 4.0f * u1 * u3) + s * u4;
}

// ---- degree-4 jet through the MLP, latency-tuned for a single wave ----------
// barrier every 2 dense rows (2-row s_load prefetch window, live ~190 regs),
// every 5 neurons in tanh phases (overlap the exp/rcp chains).
__device__ __forceinline__ void dense_tanh_n(float h[DH][5],
                                             const float* __restrict__ W,
                                             const float* __restrict__ B) {
    float u[DH][5];
    {
        float h0 = h[0][0], h1 = h[0][1], h2 = h[0][2], h3 = h[0][3], h4 = h[0][4];
#pragma unroll
        for (int j = 0; j < DH; ++j) {
            float w = W[j];
            u[j][0] = fmaf(h0, w, B[j]);
            u[j][1] = h1 * w; u[j][2] = h2 * w; u[j][3] = h3 * w; u[j][4] = h4 * w;
        }
    }
#pragma unroll
    for (int k = 1; k < DH; ++k) {
        float h0 = h[k][0], h1 = h[k][1], h2 = h[k][2], h3 = h[k][3], h4 = h[k][4];
#pragma unroll
        for (int j = 0; j < DH; ++j) {
            float w = W[k * DH + j];
            u[j][0] = fmaf(h0, w, u[j][0]);
            u[j][1] = fmaf(h1, w, u[j][1]);
            u[j][2] = fmaf(h2, w, u[j][2]);
            u[j][3] = fmaf(h3, w, u[j][3]);
            u[j][4] = fmaf(h4, w, u[j][4]);
        }
        if ((k & 1) == 0) __builtin_amdgcn_sched_barrier(0);
    }
#pragma unroll
    for (int j = 0; j < DH; ++j) {
        float hj[5];
        tanh_jet(u[j][0], u[j][1], u[j][2], u[j][3], u[j][4], hj);
        h[j][0] = hj[0]; h[j][1] = hj[1]; h[j][2] = hj[2];
        h[j][3] = hj[3]; h[j][4] = hj[4];
        if ((j % 5) == 4) __builtin_amdgcn_sched_barrier(0);
    }
}

__device__ __forceinline__ void jet_eval_n(float xv,
                                           const float* __restrict__ W1,
                                           const float* __restrict__ b1,
                                           const float* __restrict__ W2,
                                           const float* __restrict__ b2,
                                           const float* __restrict__ W3,
                                           const float* __restrict__ b3,
                                           const float* __restrict__ W4,
                                           const float* __restrict__ b4,
                                           float o[5]) {
    float h[DH][5];
#pragma unroll
    for (int j = 0; j < DH; ++j) {
        float w = W1[j];
        float t, s, f2, f3, f4;
        tanh_fs(fmaf(xv, w, b1[j]), t, s, f2, f3, f4);
        float w2 = w * w;
        h[j][0] = t; h[j][1] = s * w; h[j][2] = f2 * w2;
        h[j][3] = f3 * w2 * w; h[j][4] = f4 * w2 * w2;
        if ((j % 5) == 4) __builtin_amdgcn_sched_barrier(0);
    }
    dense_tanh_n(h, W2, b2);
    dense_tanh_n(h, W3, b3);
    float o0 = b4[0], o1 = 0.f, o2 = 0.f, o3 = 0.f, o4 = 0.f;
#pragma unroll
    for (int k = 0; k < DH; ++k) {
        float w = W4[k];
        o0 = fmaf(h[k][0], w, o0);
        o1 = fmaf(h[k][1], w, o1);
        o2 = fmaf(h[k][2], w, o2);
        o3 = fmaf(h[k][3], w, o3);
        o4 = fmaf(h[k][4], w, o4);
    }
    o[0] = o0; o[1] = o1; o[2] = o2; o[3] = o3; o[4] = o4;
}

// ---- kernel A: exact jets at 64 Chebyshev-Lobatto nodes -> DCT-I coeffs -----
// lane j: x_j = (1+cos(pi*j/63))/2 (j=0 -> x=1, j=63 -> x=0; endpoints exact).
__global__ void __launch_bounds__(64)
pinn_nodes(const float* __restrict__ W1, const float* __restrict__ b1,
           const float* __restrict__ W2, const float* __restrict__ b2,
           const float* __restrict__ W3, const float* __restrict__ b3,
           const float* __restrict__ W4, const float* __restrict__ b4,
           float* __restrict__ C, float* __restrict__ bc) {
    int j = threadIdx.x;           // 0..63
    float xv;
    if (j == 0)            xv = 1.0f;
    else if (j == M_DEG)   xv = 0.0f;
    else                   xv = 0.5f + 0.5f * __builtin_amdgcn_cosf((float)j * (1.0f / 126.0f));
    float o[5];
    jet_eval_n(xv, W1, b1, W2, b2, W3, b3, W4, b4, o);

    __shared__ float rsh[NNODES];
    rsh[j] = o[4] + 1.0f;          // PDE residual w'''' + P/(E*I)
    if (j == M_DEG) {              // x = 0 (left)
#pragma unroll
        for (int c = 0; c < 5; ++c) bc[c] = o[c];
    }
    if (j == 0) {                  // x = 1 (right)
#pragma unroll
        for (int c = 0; c < 5; ++c) bc[5 + c] = o[c];
    }
    __syncthreads();

    // DCT-I via v_cos_f32 (arg in revolutions: cos(2pi*m/126) = cos(pi*m/63)),
    // fully unrolled, 4 independent float accumulators.
    int k = j;
    float a0 = 0.f, a1 = 0.f, a2 = 0.f, a3 = 0.f;
#pragma unroll
    for (int jj = 0; jj < NNODES; ++jj) {
        int m = (jj * k) % 126;
        float cv = __builtin_amdgcn_cosf((float)m * (1.0f / 126.0f));
        float term = (jj == 0 || jj == M_DEG) ? 0.5f * rsh[jj] : rsh[jj];
        float v = term * cv;
        if ((jj & 3) == 0) a0 += v;
        else if ((jj & 3) == 1) a1 += v;
        else if ((jj & 3) == 2) a2 += v;
        else a3 += v;
    }
    float e = ((a0 + a1) + (a2 + a3)) * (2.0f / 63.0f);
    if (k == 0 || k == M_DEG) e *= 0.5f;
    C[k] = e;
}

// ---- kernel B: per-point Clenshaw (degree 63), reduce residual^2 ------------
__global__ void __launch_bounds__(256)
pinn_pde(const float* __restrict__ x, const float* __restrict__ Cc,
         double* __restrict__ partials, int N) {
    // coefficients: wave-uniform loads with compile-time indices -> SGPRs
    float e[NNODES];
#pragma unroll
    for (int k = 0; k < NNODES; ++k) e[k] = Cc[k];

    int tid = threadIdx.x;
    v2f accA = {0.f, 0.f}, accB = {0.f, 0.f};
    int i0 = blockIdx.x * blockDim.x + tid;
    int gsz = gridDim.x * blockDim.x;
    int n4 = N >> 2;
    const float4* x4 = reinterpret_cast<const float4*>(x);
    for (int i = i0; i < n4; i += gsz) {
        float4 xv = x4[i];
        v2f tA = {2.f * xv.x - 1.f, 2.f * xv.y - 1.f};
        v2f tB = {2.f * xv.z - 1.f, 2.f * xv.w - 1.f};
        v2f t2A = tA + tA, t2B = tB + tB;
        v2f b0A = {0.f, 0.f}, b1A = {0.f, 0.f};
        v2f b0B = {0.f, 0.f}, b1B = {0.f, 0.f};
#pragma unroll
        for (int k = M_DEG; k >= 1; --k) {
            v2f ek = {e[k], e[k]};
            v2f bnA = __builtin_elementwise_fma(t2A, b0A, ek) - b1A;
            b1A = b0A; b0A = bnA;
            v2f bnB = __builtin_elementwise_fma(t2B, b0B, ek) - b1B;
            b1B = b0B; b0B = bnB;
        }
        v2f e0 = {e[0], e[0]};
        v2f rA = __builtin_elementwise_fma(tA, b0A, e0) - b1A;
        v2f rB = __builtin_elementwise_fma(tB, b0B, e0) - b1B;
        accA = __builtin_elementwise_fma(rA, rA, accA);
        accB = __builtin_elementwise_fma(rB, rB, accB);
    }
    float accs = (accA.x + accA.y) + (accB.x + accB.y);
    // scalar tail (N % 4 != 0)
    for (int i = (n4 << 2) + i0; i < N; i += gsz) {
        float t = 2.f * x[i] - 1.f, t2 = t + t;
        float b0 = 0.f, b1 = 0.f;
#pragma unroll
        for (int k = M_DEG; k >= 1; --k) {
            float bn = fmaf(t2, b0, e[k]) - b1;
            b1 = b0; b0 = bn;
        }
        float r = fmaf(t, b0, e[0]) - b1;
        accs = fmaf(r, r, accs);
    }

    double a = (double)accs;
#pragma unroll
    for (int off = 32; off > 0; off >>= 1) a += __shfl_down(a, off, 64);
    __shared__ double red[4];
    int lane = tid & 63, wid = tid >> 6;
    if (lane == 0) red[wid] = a;
    __syncthreads();
    if (tid == 0) partials[blockIdx.x] = red[0] + red[1] + red[2] + red[3];
}

// ---- finish: reduce partials, combine with BC jets, write scalars -----------
__global__ void __launch_bounds__(256)
pinn_finish(const double* __restrict__ partials, int nparts,
            const float* __restrict__ bc,
            float* __restrict__ out, int N, float* __restrict__ consts) {
    int tid = threadIdx.x;
    double a = 0.0;
    for (int i = tid; i < nparts; i += 256) a += partials[i];
#pragma unroll
    for (int off = 32; off > 0; off >>= 1) a += __shfl_down(a, off, 64);
    __shared__ double red[4];
    if ((tid & 63) == 0) red[tid >> 6] = a;
    __syncthreads();
    if (tid == 0) {
        double total = red[0] + red[1] + red[2] + red[3];
        float pdef = (float)(total / (double)N);
        float lbw  = bc[0] * bc[0];   // w(0)^2
        float lbwx = bc[1] * bc[1];   // w_x(0)^2
        float rbM  = bc[7] * bc[7];   // w_xx(1)^2
        float rbw  = bc[5] * bc[5];   // w(1)^2
        float loss = pdef + lbw + lbwx + rbM + rbw;  // reference add order
        consts[0] = loss; consts[1] = lbw; consts[2] = lbwx;
        consts[3] = rbM;  consts[4] = rbw;
        out[N] = pdef;   // pde_loss scalar
    }
}

// ---- fill: broadcast 5 constants into their [N] regions ---------------------
__global__ void __launch_bounds__(256)
pinn_fill(float* __restrict__ out, const float* __restrict__ consts, int N) {
    int r = blockIdx.y;                       // 0:loss 1:lbw 2:lbwx 3:rbM 4:rbw
    float c = consts[r];
    size_t base = (r == 0) ? 0 : ((size_t)r * (size_t)N + 1);
    float* p = out + base;
    size_t tid = (size_t)blockIdx.x * blockDim.x + threadIdx.x;
    size_t stride = (size_t)gridDim.x * blockDim.x;
    size_t head = ((16 - ((size_t)p & 15)) & 15) >> 2;  // floats to 16B align
    size_t n = (size_t)N;
    if (head > n) head = n;
    if (tid < head) p[tid] = c;
    size_t n4 = (n - head) >> 2;
    float4* p4 = reinterpret_cast<float4*>(p + head);
    float4 cv = {c, c, c, c};
    for (size_t i = tid; i < n4; i += stride) p4[i] = cv;
    size_t done = head + (n4 << 2);
    size_t t = done + tid;
    if (t < n) p[t] = c;
}

extern "C" void kernel_launch(void* const* d_in, const int* in_sizes, int n_in,
                              void* d_out, int out_size, void* d_ws, size_t ws_size,
                              hipStream_t stream) {
    const float* x  = (const float*)d_in[0];
    const float* W1 = (const float*)d_in[1];
    const float* b1 = (const float*)d_in[2];
    const float* W2 = (const float*)d_in[3];
    const float* b2 = (const float*)d_in[4];
    const float* W3 = (const float*)d_in[5];
    const float* b3 = (const float*)d_in[6];
    const float* W4 = (const float*)d_in[7];
    const float* b4 = (const float*)d_in[8];
    float* out = (float*)d_out;
    int N = in_sizes[0];

    // ws layout: C[64] @0 | bc[10] @256B | consts[8] @384B | partials @1024B
    float*  C        = (float*)d_ws;
    float*  bc       = (float*)((char*)d_ws + 256);
    float*  consts   = (float*)((char*)d_ws + 384);
    double* partials = (double*)((char*)d_ws + 1024);

    int NB = 512;
    size_t need = 1024 + (size_t)NB * 8;
    if (ws_size < need) {
        NB = (int)((ws_size > 1024 + 8) ? (ws_size - 1024) / 8 : 1);
        if (NB < 1) NB = 1;
        if (NB > 512) NB = 512;
    }

    hipLaunchKernelGGL(pinn_nodes, dim3(1), dim3(64), 0, stream,
                       W1, b1, W2, b2, W3, b3, W4, b4, C, bc);
    hipLaunchKernelGGL(pinn_pde, dim3(NB), dim3(256), 0, stream,
                       x, C, partials, N);
    hipLaunchKernelGGL(pinn_finish, dim3(1), dim3(256), 0, stream,
                       partials, NB, bc, out, N, consts);
    int gx = (N / 4 + 255) / 256;
    if (gx > 1024) gx = 1024;
    if (gx < 1) gx = 1;
    hipLaunchKernelGGL(pinn_fill, dim3(gx, 5), dim3(256), 0, stream,
                       out, consts, N);
}